// Round 2
// baseline (1063.244 us; speedup 1.0000x reference)
//
#include <hip/hip_runtime.h>
#include <hip/hip_bf16.h>

#define DFEAT 64
#define EPSBN 1e-5f
#define SCB 2048   // elements per scan block (256 threads x 8)

// ---------------- degree histogram (int atomics) ----------------
__global__ void hist_kernel(const int* __restrict__ src, const int* __restrict__ dst,
                            int* __restrict__ deg_out, int* __restrict__ deg_in, int E) {
    int e = blockIdx.x * blockDim.x + threadIdx.x;
    if (e < E) {
        atomicAdd(&deg_out[src[e]], 1);
        atomicAdd(&deg_in[dst[e]], 1);
    }
}

// ---------------- scan pass 1: per-block sums of deg_in ----------------
__global__ void scan1_kernel(const int* __restrict__ deg, int* __restrict__ bsum, int N) {
    __shared__ int red[256];
    int t = threadIdx.x;
    int base = blockIdx.x * SCB + t * 8;
    int s = 0;
    #pragma unroll
    for (int j = 0; j < 8; ++j) { int idx = base + j; if (idx < N) s += deg[idx]; }
    red[t] = s;
    __syncthreads();
    for (int d = 128; d > 0; d >>= 1) { if (t < d) red[t] += red[t + d]; __syncthreads(); }
    if (t == 0) bsum[blockIdx.x] = red[0];
}

// ---------------- scan pass 2: exclusive scan of block sums (tiny) ----------------
__global__ void scan2_kernel(int* __restrict__ bsum, int* __restrict__ row_start, int NB, int N) {
    if (threadIdx.x == 0 && blockIdx.x == 0) {
        int run = 0;
        for (int b = 0; b < NB; ++b) { int v = bsum[b]; bsum[b] = run; run += v; }
        row_start[N] = run;   // == E
    }
}

// ---------------- scan pass 3: full exclusive scan -> row_start ----------------
__global__ void scan3_kernel(const int* __restrict__ deg, const int* __restrict__ bsum,
                             int* __restrict__ row_start, int N) {
    __shared__ int sc[256];
    int t = threadIdx.x;
    int base = blockIdx.x * SCB + t * 8;
    int v[8], ex[8];
    int s = 0;
    #pragma unroll
    for (int j = 0; j < 8; ++j) {
        int idx = base + j;
        v[j] = (idx < N) ? deg[idx] : 0;
        ex[j] = s;
        s += v[j];
    }
    sc[t] = s;
    __syncthreads();
    for (int d = 1; d < 256; d <<= 1) {
        int vv = (t >= d) ? sc[t - d] : 0;
        __syncthreads();
        sc[t] += vv;
        __syncthreads();
    }
    int toff = sc[t] - s + bsum[blockIdx.x];
    #pragma unroll
    for (int j = 0; j < 8; ++j) {
        int idx = base + j;
        if (idx < N) row_start[idx] = toff + ex[j];
    }
}

// ---------------- counting-sort edges by dst, pack (src, coef) ----------------
__global__ void fill_kernel(const int* __restrict__ src, const int* __restrict__ dst,
                            const int* __restrict__ deg_out, const int* __restrict__ row_start,
                            int* __restrict__ cursor, int2* __restrict__ epack, int E) {
    int e = blockIdx.x * blockDim.x + threadIdx.x;
    if (e < E) {
        int d = dst[e], s = src[e];
        int pos = atomicAdd(&cursor[d], 1);
        float coef = rsqrtf((float)max(deg_out[s], 1));
        epack[row_start[d] + pos] = make_int2(s, __float_as_int(coef));
    }
}

// ---------------- fused gather-SpMM + GEMM + BN stats ----------------
// one block = one 64-row tile. Gather: lane=feature. GEMM: lane=row, wave w -> 16 cols.
__global__ __launch_bounds__(256) void gather_gemm_kernel(
        const float* __restrict__ x, const int* __restrict__ row_start,
        const int2* __restrict__ epack, const float* __restrict__ W,
        const float* __restrict__ bvec, float* __restrict__ y,
        float* __restrict__ sums, float* __restrict__ sumsq, int N) {
    __shared__ float A[64][65];   // pad -> conflict-free row & col access
    int tid = threadIdx.x;
    int w = tid >> 6;
    int lane = tid & 63;
    int r0 = blockIdx.x * 64;

    // ---- gather phase: each wave produces 16 rows of A ----
    for (int i = 0; i < 16; ++i) {
        int rl = w * 16 + i;
        int r = r0 + rl;
        float acc = 0.f;
        if (r < N) {
            int beg = row_start[r];
            int end = row_start[r + 1];
            for (int e = beg; e < end; ++e) {
                int2 p = epack[e];                       // broadcast load (all lanes same addr)
                acc += x[(size_t)p.x * DFEAT + lane] * __int_as_float(p.y);
            }
            acc *= rsqrtf((float)max(end - beg, 1));     // norm_dst
        }
        A[rl][lane] = acc;
    }
    __syncthreads();

    // ---- GEMM phase: lane = row-in-tile, wave wu covers cols [wu*16, wu*16+16) ----
    int wu = __builtin_amdgcn_readfirstlane(w);          // force wave-uniform -> scalar W loads
    int c0 = wu * 16;
    float acc16[16];
    #pragma unroll
    for (int cc = 0; cc < 16; ++cc) acc16[cc] = bvec[c0 + cc];

    #pragma unroll 8
    for (int k = 0; k < 64; ++k) {
        float a = A[lane][k];                            // bank (lane+k)%32 -> 2-way, free
        const float* wr = &W[k * DFEAT + c0];            // wave-uniform address
        #pragma unroll
        for (int cc = 0; cc < 16; ++cc) acc16[cc] += a * wr[cc];
    }

    int r = r0 + lane;
    if (r < N) {
        float4* yp = (float4*)&y[(size_t)r * DFEAT + c0];
        yp[0] = make_float4(acc16[0],  acc16[1],  acc16[2],  acc16[3]);
        yp[1] = make_float4(acc16[4],  acc16[5],  acc16[6],  acc16[7]);
        yp[2] = make_float4(acc16[8],  acc16[9],  acc16[10], acc16[11]);
        yp[3] = make_float4(acc16[12], acc16[13], acc16[14], acc16[15]);
    } else {
        #pragma unroll
        for (int cc = 0; cc < 16; ++cc) acc16[cc] = 0.f;  // pad rows contribute 0 to BN stats
    }

    // ---- BN stats: reduce over lanes (= rows), one atomic per col per wave ----
    #pragma unroll
    for (int cc = 0; cc < 16; ++cc) {
        float v1 = acc16[cc];
        float v2 = acc16[cc] * acc16[cc];
        for (int off = 32; off > 0; off >>= 1) {
            v1 += __shfl_down(v1, off);
            v2 += __shfl_down(v2, off);
        }
        if (lane == 0) {
            atomicAdd(&sums[c0 + cc], v1);
            atomicAdd(&sumsq[c0 + cc], v2);
        }
    }
}

// ---------------- BN (batch stats) + ReLU + residual, in place on y ----------------
__global__ void bn_relu_res_kernel(const float* __restrict__ x,
                                   const float* __restrict__ sums,
                                   const float* __restrict__ sumsq,
                                   const float* __restrict__ gamma,
                                   const float* __restrict__ beta,
                                   float* __restrict__ y, int total, float inv_n) {
    int i = blockIdx.x * blockDim.x + threadIdx.x;
    if (i < total) {
        int c = i & (DFEAT - 1);
        float mean = sums[c] * inv_n;
        float var = sumsq[c] * inv_n - mean * mean;
        float inv = rsqrtf(var + EPSBN);
        float v = (y[i] - mean) * inv * gamma[c] + beta[c];
        v = fmaxf(v, 0.f);
        y[i] = x[i] + v;
    }
}

extern "C" void kernel_launch(void* const* d_in, const int* in_sizes, int n_in,
                              void* d_out, int out_size, void* d_ws, size_t ws_size,
                              hipStream_t stream) {
    const float* x     = (const float*)d_in[0];
    const int*   src   = (const int*)d_in[1];
    const int*   dst   = (const int*)d_in[2];
    const float* W     = (const float*)d_in[3];
    const float* bvec  = (const float*)d_in[4];
    const float* gamma = (const float*)d_in[5];
    const float* beta  = (const float*)d_in[6];
    float* out = (float*)d_out;

    const int n_nodes = in_sizes[0] / DFEAT;
    const int E = in_sizes[1];
    const int NB = (n_nodes + SCB - 1) / SCB;

    // workspace layout (ints)
    int* wsi = (int*)d_ws;
    int*   deg_out_i = wsi;                      // N
    int*   deg_in_i  = deg_out_i + n_nodes;      // N
    int*   cursor    = deg_in_i + n_nodes;       // N
    float* sums      = (float*)(cursor + n_nodes);        // 64
    float* sumsq     = sums + DFEAT;                      // 64
    int*   row_start = (int*)(sumsq + DFEAT);             // N+1
    int*   bsum      = row_start + n_nodes + 1;           // NB (<=64)
    int2*  epack     = (int2*)(bsum + 64);                // E

    // zero: deg_out, deg_in, cursor, sums, sumsq (everything else fully overwritten)
    size_t zero_bytes = (3 * (size_t)n_nodes + 2 * DFEAT) * sizeof(int);
    hipMemsetAsync(d_ws, 0, zero_bytes, stream);

    hist_kernel<<<(E + 255) / 256, 256, 0, stream>>>(src, dst, deg_out_i, deg_in_i, E);

    scan1_kernel<<<NB, 256, 0, stream>>>(deg_in_i, bsum, n_nodes);
    scan2_kernel<<<1, 64, 0, stream>>>(bsum, row_start, NB, n_nodes);
    scan3_kernel<<<NB, 256, 0, stream>>>(deg_in_i, bsum, row_start, n_nodes);

    fill_kernel<<<(E + 255) / 256, 256, 0, stream>>>(src, dst, deg_out_i, row_start,
                                                     cursor, epack, E);

    int ntiles = (n_nodes + 63) / 64;
    gather_gemm_kernel<<<ntiles, 256, 0, stream>>>(x, row_start, epack, W, bvec,
                                                   out, sums, sumsq, n_nodes);

    int total = n_nodes * DFEAT;
    bn_relu_res_kernel<<<(total + 255) / 256, 256, 0, stream>>>(
        x, sums, sumsq, gamma, beta, out, total, 1.0f / (float)n_nodes);
}

// Round 3
// 995.091 us; speedup vs baseline: 1.0685x; 1.0685x over previous
//
#include <hip/hip_runtime.h>
#include <hip/hip_bf16.h>

#define DFEAT 64
#define EPSBN 1e-5f
#define SCB 2048   // elements per scan block (256 threads x 8)

// ---------------- degree histogram (int atomics) ----------------
__global__ void hist_kernel(const int* __restrict__ src, const int* __restrict__ dst,
                            int* __restrict__ deg_out, int* __restrict__ deg_in, int E) {
    int e = blockIdx.x * blockDim.x + threadIdx.x;
    if (e < E) {
        atomicAdd(&deg_out[src[e]], 1);
        atomicAdd(&deg_in[dst[e]], 1);
    }
}

// ---------------- scan pass 1: per-block sums of deg_in ----------------
__global__ void scan1_kernel(const int* __restrict__ deg, int* __restrict__ bsum, int N) {
    __shared__ int red[256];
    int t = threadIdx.x;
    int base = blockIdx.x * SCB + t * 8;
    int s = 0;
    #pragma unroll
    for (int j = 0; j < 8; ++j) { int idx = base + j; if (idx < N) s += deg[idx]; }
    red[t] = s;
    __syncthreads();
    for (int d = 128; d > 0; d >>= 1) { if (t < d) red[t] += red[t + d]; __syncthreads(); }
    if (t == 0) bsum[blockIdx.x] = red[0];
}

// ---------------- scan pass 2: one-wave shuffle exclusive scan of block sums ----------------
// assumes NB <= 64
__global__ void scan2_kernel(int* __restrict__ bsum, int* __restrict__ row_start, int NB, int N) {
    int lane = threadIdx.x & 63;
    int v = (lane < NB) ? bsum[lane] : 0;
    int incl = v;
    #pragma unroll
    for (int off = 1; off < 64; off <<= 1) {
        int t = __shfl_up(incl, off);
        if (lane >= off) incl += t;
    }
    if (lane < NB) bsum[lane] = incl - v;
    if (lane == 63) row_start[N] = incl;   // total == E
}

// ---------------- scan pass 3: full exclusive scan -> row_start ----------------
__global__ void scan3_kernel(const int* __restrict__ deg, const int* __restrict__ bsum,
                             int* __restrict__ row_start, int N) {
    __shared__ int sc[256];
    int t = threadIdx.x;
    int base = blockIdx.x * SCB + t * 8;
    int v[8], ex[8];
    int s = 0;
    #pragma unroll
    for (int j = 0; j < 8; ++j) {
        int idx = base + j;
        v[j] = (idx < N) ? deg[idx] : 0;
        ex[j] = s;
        s += v[j];
    }
    sc[t] = s;
    __syncthreads();
    for (int d = 1; d < 256; d <<= 1) {
        int vv = (t >= d) ? sc[t - d] : 0;
        __syncthreads();
        sc[t] += vv;
        __syncthreads();
    }
    int toff = sc[t] - s + bsum[blockIdx.x];
    #pragma unroll
    for (int j = 0; j < 8; ++j) {
        int idx = base + j;
        if (idx < N) row_start[idx] = toff + ex[j];
    }
}

// ---------------- counting-sort edges by dst, pack (src, coef) + local row byte ----------------
__global__ void fill_kernel(const int* __restrict__ src, const int* __restrict__ dst,
                            const int* __restrict__ deg_out, const int* __restrict__ row_start,
                            int* __restrict__ cursor, int2* __restrict__ epack,
                            unsigned char* __restrict__ erow, int E) {
    int e = blockIdx.x * blockDim.x + threadIdx.x;
    if (e < E) {
        int d = dst[e], s = src[e];
        int pos = atomicAdd(&cursor[d], 1);
        float coef = rsqrtf((float)max(deg_out[s], 1));
        int idx = row_start[d] + pos;
        epack[idx] = make_int2(s, __float_as_int(coef));
        erow[idx] = (unsigned char)(d & 63);   // tile-local row (tiles are 64-aligned)
    }
}

// ---------------- fused gather-SpMM + GEMM + BN stats ----------------
// one block = one 64-row dst tile; 8 waves. Gather: edge-parallel, unroll x4,
// LDS fp32 atomics (edges dst-sorted -> wave-uniform row, run-merge). GEMM:
// lane=row, wave w -> 8 cols.
__global__ __launch_bounds__(512) void gather_gemm_kernel(
        const float* __restrict__ x, const int* __restrict__ row_start,
        const int2* __restrict__ epack, const unsigned char* __restrict__ erow,
        const float* __restrict__ W, const float* __restrict__ bvec,
        float* __restrict__ y, float* __restrict__ sums, float* __restrict__ sumsq,
        int N) {
    __shared__ float A[64][65];
    int tid = threadIdx.x;
    int w = tid >> 6;
    int lane = tid & 63;
    int r0 = blockIdx.x * 64;

    for (int i = w; i < 64; i += 8) A[i][lane] = 0.f;
    __syncthreads();

    int gbeg = row_start[r0];
    int rend = min(r0 + 64, N);
    int gend = row_start[rend];
    int total = gend - gbeg;
    int chunk = (total + 7) >> 3;
    int cbeg = gbeg + w * chunk;
    int cend = min(cbeg + chunk, gend);

    int e = cbeg;
    for (; e + 4 <= cend; e += 4) {
        int2 p0 = epack[e + 0], p1 = epack[e + 1], p2 = epack[e + 2], p3 = epack[e + 3];
        int q0 = erow[e + 0], q1 = erow[e + 1], q2 = erow[e + 2], q3 = erow[e + 3];
        float v0 = x[(size_t)p0.x * DFEAT + lane] * __int_as_float(p0.y);
        float v1 = x[(size_t)p1.x * DFEAT + lane] * __int_as_float(p1.y);
        float v2 = x[(size_t)p2.x * DFEAT + lane] * __int_as_float(p2.y);
        float v3 = x[(size_t)p3.x * DFEAT + lane] * __int_as_float(p3.y);
        // q* are wave-uniform (scalar per edge) -> branches are non-divergent
        if (q0 == q1 && q1 == q2 && q2 == q3) {
            atomicAdd(&A[q0][lane], (v0 + v1) + (v2 + v3));
        } else {
            if (q0 == q1) atomicAdd(&A[q0][lane], v0 + v1);
            else { atomicAdd(&A[q0][lane], v0); atomicAdd(&A[q1][lane], v1); }
            if (q2 == q3) atomicAdd(&A[q2][lane], v2 + v3);
            else { atomicAdd(&A[q2][lane], v2); atomicAdd(&A[q3][lane], v3); }
        }
    }
    for (; e < cend; ++e) {
        int2 p = epack[e];
        int q = erow[e];
        atomicAdd(&A[q][lane], x[(size_t)p.x * DFEAT + lane] * __int_as_float(p.y));
    }
    __syncthreads();

    // norm_dst scaling
    for (int i = w; i < 64; i += 8) {
        int r = r0 + i;
        if (r < N) {
            int deg = row_start[r + 1] - row_start[r];
            A[i][lane] *= rsqrtf((float)max(deg, 1));
        }
    }
    __syncthreads();

    // GEMM: lane = row-in-tile, wave wu covers cols [wu*8, wu*8+8)
    int wu = __builtin_amdgcn_readfirstlane(w);
    int c0 = wu * 8;
    float acc[8];
    #pragma unroll
    for (int cc = 0; cc < 8; ++cc) acc[cc] = bvec[c0 + cc];

    #pragma unroll 8
    for (int k = 0; k < 64; ++k) {
        float a = A[lane][k];                    // (lane+k)%32 -> 2-way, free
        const float* wr = &W[k * DFEAT + c0];    // wave-uniform -> scalar loads
        #pragma unroll
        for (int cc = 0; cc < 8; ++cc) acc[cc] += a * wr[cc];
    }

    int r = r0 + lane;
    if (r < N) {
        float4* yp = (float4*)&y[(size_t)r * DFEAT + c0];
        yp[0] = make_float4(acc[0], acc[1], acc[2], acc[3]);
        yp[1] = make_float4(acc[4], acc[5], acc[6], acc[7]);
    } else {
        #pragma unroll
        for (int cc = 0; cc < 8; ++cc) acc[cc] = 0.f;   // pad rows contribute 0 to BN stats
    }

    #pragma unroll
    for (int cc = 0; cc < 8; ++cc) {
        float v1 = acc[cc];
        float v2 = acc[cc] * acc[cc];
        for (int off = 32; off > 0; off >>= 1) {
            v1 += __shfl_down(v1, off);
            v2 += __shfl_down(v2, off);
        }
        if (lane == 0) {
            atomicAdd(&sums[c0 + cc], v1);
            atomicAdd(&sumsq[c0 + cc], v2);
        }
    }
}

// ---------------- BN (batch stats) + ReLU + residual, in place on y ----------------
__global__ void bn_relu_res_kernel(const float* __restrict__ x,
                                   const float* __restrict__ sums,
                                   const float* __restrict__ sumsq,
                                   const float* __restrict__ gamma,
                                   const float* __restrict__ beta,
                                   float* __restrict__ y, int total, float inv_n) {
    int i = blockIdx.x * blockDim.x + threadIdx.x;
    if (i < total) {
        int c = i & (DFEAT - 1);
        float mean = sums[c] * inv_n;
        float var = sumsq[c] * inv_n - mean * mean;
        float inv = rsqrtf(var + EPSBN);
        float v = (y[i] - mean) * inv * gamma[c] + beta[c];
        v = fmaxf(v, 0.f);
        y[i] = x[i] + v;
    }
}

extern "C" void kernel_launch(void* const* d_in, const int* in_sizes, int n_in,
                              void* d_out, int out_size, void* d_ws, size_t ws_size,
                              hipStream_t stream) {
    const float* x     = (const float*)d_in[0];
    const int*   src   = (const int*)d_in[1];
    const int*   dst   = (const int*)d_in[2];
    const float* W     = (const float*)d_in[3];
    const float* bvec  = (const float*)d_in[4];
    const float* gamma = (const float*)d_in[5];
    const float* beta  = (const float*)d_in[6];
    float* out = (float*)d_out;

    const int n_nodes = in_sizes[0] / DFEAT;
    const int E = in_sizes[1];
    const int NB = (n_nodes + SCB - 1) / SCB;

    // workspace layout: epack first (8B alignment), then zeroable int block,
    // then row_start/bsum, then erow bytes
    char* wsb = (char*)d_ws;
    int2* epack      = (int2*)wsb;                        // E
    int*  deg_out_i  = (int*)(wsb + (size_t)E * 8);       // N   <- zeroed
    int*  deg_in_i   = deg_out_i + n_nodes;               // N   <- zeroed
    int*  cursor     = deg_in_i + n_nodes;                // N   <- zeroed
    float* sums      = (float*)(cursor + n_nodes);        // 64  <- zeroed
    float* sumsq     = sums + DFEAT;                      // 64  <- zeroed
    int*  row_start  = (int*)(sumsq + DFEAT);             // N+1
    int*  bsum       = row_start + n_nodes + 1;           // NB (<=64)
    unsigned char* erow = (unsigned char*)(bsum + 64);    // E

    size_t zero_bytes = (3 * (size_t)n_nodes + 2 * DFEAT) * sizeof(int);
    hipMemsetAsync(deg_out_i, 0, zero_bytes, stream);

    hist_kernel<<<(E + 255) / 256, 256, 0, stream>>>(src, dst, deg_out_i, deg_in_i, E);

    scan1_kernel<<<NB, 256, 0, stream>>>(deg_in_i, bsum, n_nodes);
    scan2_kernel<<<1, 64, 0, stream>>>(bsum, row_start, NB, n_nodes);
    scan3_kernel<<<NB, 256, 0, stream>>>(deg_in_i, bsum, row_start, n_nodes);

    fill_kernel<<<(E + 255) / 256, 256, 0, stream>>>(src, dst, deg_out_i, row_start,
                                                     cursor, epack, erow, E);

    int ntiles = (n_nodes + 63) / 64;
    gather_gemm_kernel<<<ntiles, 512, 0, stream>>>(x, row_start, epack, erow, W, bvec,
                                                   out, sums, sumsq, n_nodes);

    int total = n_nodes * DFEAT;
    bn_relu_res_kernel<<<(total + 255) / 256, 256, 0, stream>>>(
        x, sums, sumsq, gamma, beta, out, total, 1.0f / (float)n_nodes);
}

// Round 4
// 966.536 us; speedup vs baseline: 1.1001x; 1.0295x over previous
//
#include <hip/hip_runtime.h>
#include <hip/hip_bf16.h>

#define DFEAT 64
#define EPSBN 1e-5f
#define SCB 2048   // elements per scan block (256 threads x 8)

// ---------------- degree histogram (int atomics) ----------------
__global__ void hist_kernel(const int* __restrict__ src, const int* __restrict__ dst,
                            int* __restrict__ deg_out, int* __restrict__ deg_in, int E) {
    int e = blockIdx.x * blockDim.x + threadIdx.x;
    if (e < E) {
        atomicAdd(&deg_out[src[e]], 1);
        atomicAdd(&deg_in[dst[e]], 1);
    }
}

// ---------------- scan pass 1: per-block sums of deg_in ----------------
__global__ void scan1_kernel(const int* __restrict__ deg, int* __restrict__ bsum, int N) {
    __shared__ int red[256];
    int t = threadIdx.x;
    int base = blockIdx.x * SCB + t * 8;
    int s = 0;
    #pragma unroll
    for (int j = 0; j < 8; ++j) { int idx = base + j; if (idx < N) s += deg[idx]; }
    red[t] = s;
    __syncthreads();
    for (int d = 128; d > 0; d >>= 1) { if (t < d) red[t] += red[t + d]; __syncthreads(); }
    if (t == 0) bsum[blockIdx.x] = red[0];
}

// ---------------- scan pass 2: one-wave shuffle exclusive scan (NB <= 64) ----------------
__global__ void scan2_kernel(int* __restrict__ bsum, int* __restrict__ row_start, int NB, int N) {
    int lane = threadIdx.x & 63;
    int v = (lane < NB) ? bsum[lane] : 0;
    int incl = v;
    #pragma unroll
    for (int off = 1; off < 64; off <<= 1) {
        int t = __shfl_up(incl, off);
        if (lane >= off) incl += t;
    }
    if (lane < NB) bsum[lane] = incl - v;
    if (lane == 63) row_start[N] = incl;   // total == E
}

// ---------------- scan pass 3: full exclusive scan -> row_start ----------------
__global__ void scan3_kernel(const int* __restrict__ deg, const int* __restrict__ bsum,
                             int* __restrict__ row_start, int N) {
    __shared__ int sc[256];
    int t = threadIdx.x;
    int base = blockIdx.x * SCB + t * 8;
    int v[8], ex[8];
    int s = 0;
    #pragma unroll
    for (int j = 0; j < 8; ++j) {
        int idx = base + j;
        v[j] = (idx < N) ? deg[idx] : 0;
        ex[j] = s;
        s += v[j];
    }
    sc[t] = s;
    __syncthreads();
    for (int d = 1; d < 256; d <<= 1) {
        int vv = (t >= d) ? sc[t - d] : 0;
        __syncthreads();
        sc[t] += vv;
        __syncthreads();
    }
    int toff = sc[t] - s + bsum[blockIdx.x];
    #pragma unroll
    for (int j = 0; j < 8; ++j) {
        int idx = base + j;
        if (idx < N) row_start[idx] = toff + ex[j];
    }
}

// ---------------- counting-sort edges by dst, pack (src, coef) ----------------
__global__ void fill_kernel(const int* __restrict__ src, const int* __restrict__ dst,
                            const int* __restrict__ deg_out, const int* __restrict__ row_start,
                            int* __restrict__ cursor, int2* __restrict__ epack, int E) {
    int e = blockIdx.x * blockDim.x + threadIdx.x;
    if (e < E) {
        int d = dst[e], s = src[e];
        int pos = atomicAdd(&cursor[d], 1);
        float coef = rsqrtf((float)max(deg_out[s], 1));
        epack[row_start[d] + pos] = make_int2(s, __float_as_int(coef));
    }
}

// ---------------- fused gather-SpMM + GEMM + BN stats ----------------
// one block = one 64-row dst tile; 8 waves of 64. Gather: one row per wave at
// a time; the row's edge descriptors are prefetched with ONE coalesced load
// (epack[beg+lane]) into the wave's registers, then shfl-broadcast feeds
// batches of 8 INDEPENDENT x-row loads (explicit MLP, no LDS atomics).
// GEMM: lane=row, wave w -> 8 cols, W in LDS.
__global__ __launch_bounds__(512) void gather_gemm_kernel(
        const float* __restrict__ x, const int* __restrict__ row_start,
        const int2* __restrict__ epack, const float* __restrict__ W,
        const float* __restrict__ bvec, float* __restrict__ y,
        float* __restrict__ sums, float* __restrict__ sumsq, int N) {
    __shared__ float Wlds[DFEAT * DFEAT];
    __shared__ float A[64][65];
    int tid = threadIdx.x;
    int w = tid >> 6;
    int lane = tid & 63;
    int r0 = blockIdx.x * 64;

    for (int i = tid; i < DFEAT * DFEAT; i += 512) Wlds[i] = W[i];

    // ---- gather: each wave produces rows w*8 .. w*8+7 of the tile ----
    for (int i = 0; i < 8; ++i) {
        int rl = w * 8 + i;
        int r = r0 + rl;
        float acc = 0.f;
        if (r < N) {
            int beg = row_start[r];
            int end = row_start[r + 1];
            for (int cb = beg; cb < end; cb += 64) {
                int take = min(64, end - cb);
                int2 p = (lane < take) ? epack[cb + lane] : make_int2(0, 0);
                int j = 0;
                for (; j + 8 <= take; j += 8) {
                    int   sj[8];
                    float cj[8];
                    float v[8];
                    #pragma unroll
                    for (int u = 0; u < 8; ++u) {
                        sj[u] = __shfl(p.x, j + u);
                        cj[u] = __int_as_float(__shfl(p.y, j + u));
                    }
                    #pragma unroll
                    for (int u = 0; u < 8; ++u) v[u] = x[(size_t)sj[u] * DFEAT + lane];
                    #pragma unroll
                    for (int u = 0; u < 8; ++u) acc = fmaf(v[u], cj[u], acc);
                }
                for (; j < take; ++j) {
                    int s = __shfl(p.x, j);
                    float c = __int_as_float(__shfl(p.y, j));
                    acc = fmaf(x[(size_t)s * DFEAT + lane], c, acc);
                }
            }
            acc *= rsqrtf((float)max(end - beg, 1));   // norm_dst
        }
        A[rl][lane] = acc;   // wave owns the row: plain store
    }
    __syncthreads();

    // ---- GEMM: lane = row-in-tile, wave wu covers cols [wu*8, wu*8+8) ----
    int wu = __builtin_amdgcn_readfirstlane(w);
    int c0 = wu * 8;
    float acc[8];
    #pragma unroll
    for (int cc = 0; cc < 8; ++cc) acc[cc] = bvec[c0 + cc];

    #pragma unroll 8
    for (int k = 0; k < 64; ++k) {
        float a = A[lane][k];                        // (lane+k)%32 -> 2-way, free
        const float* wr = &Wlds[k * DFEAT + c0];     // wave-uniform LDS broadcast
        #pragma unroll
        for (int cc = 0; cc < 8; ++cc) acc[cc] = fmaf(a, wr[cc], acc[cc]);
    }

    int r = r0 + lane;
    if (r < N) {
        float4* yp = (float4*)&y[(size_t)r * DFEAT + c0];
        yp[0] = make_float4(acc[0], acc[1], acc[2], acc[3]);
        yp[1] = make_float4(acc[4], acc[5], acc[6], acc[7]);
    } else {
        #pragma unroll
        for (int cc = 0; cc < 8; ++cc) acc[cc] = 0.f;   // pad rows: 0 into BN stats
    }

    // ---- BN stats: reduce over lanes (= rows), 8 atomics per wave ----
    #pragma unroll
    for (int cc = 0; cc < 8; ++cc) {
        float v1 = acc[cc];
        float v2 = acc[cc] * acc[cc];
        for (int off = 32; off > 0; off >>= 1) {
            v1 += __shfl_down(v1, off);
            v2 += __shfl_down(v2, off);
        }
        if (lane == 0) {
            atomicAdd(&sums[c0 + cc], v1);
            atomicAdd(&sumsq[c0 + cc], v2);
        }
    }
}

// ---------------- BN (batch stats) + ReLU + residual, in place on y ----------------
__global__ void bn_relu_res_kernel(const float* __restrict__ x,
                                   const float* __restrict__ sums,
                                   const float* __restrict__ sumsq,
                                   const float* __restrict__ gamma,
                                   const float* __restrict__ beta,
                                   float* __restrict__ y, int total, float inv_n) {
    int i = blockIdx.x * blockDim.x + threadIdx.x;
    if (i < total) {
        int c = i & (DFEAT - 1);
        float mean = sums[c] * inv_n;
        float var = sumsq[c] * inv_n - mean * mean;
        float inv = rsqrtf(var + EPSBN);
        float v = (y[i] - mean) * inv * gamma[c] + beta[c];
        v = fmaxf(v, 0.f);
        y[i] = x[i] + v;
    }
}

extern "C" void kernel_launch(void* const* d_in, const int* in_sizes, int n_in,
                              void* d_out, int out_size, void* d_ws, size_t ws_size,
                              hipStream_t stream) {
    const float* x     = (const float*)d_in[0];
    const int*   src   = (const int*)d_in[1];
    const int*   dst   = (const int*)d_in[2];
    const float* W     = (const float*)d_in[3];
    const float* bvec  = (const float*)d_in[4];
    const float* gamma = (const float*)d_in[5];
    const float* beta  = (const float*)d_in[6];
    float* out = (float*)d_out;

    const int n_nodes = in_sizes[0] / DFEAT;
    const int E = in_sizes[1];
    const int NB = (n_nodes + SCB - 1) / SCB;

    // workspace layout: epack first (8B alignment), then zeroable int block
    char* wsb = (char*)d_ws;
    int2* epack      = (int2*)wsb;                        // E
    int*  deg_out_i  = (int*)(wsb + (size_t)E * 8);       // N   <- zeroed
    int*  deg_in_i   = deg_out_i + n_nodes;               // N   <- zeroed
    int*  cursor     = deg_in_i + n_nodes;                // N   <- zeroed
    float* sums      = (float*)(cursor + n_nodes);        // 64  <- zeroed
    float* sumsq     = sums + DFEAT;                      // 64  <- zeroed
    int*  row_start  = (int*)(sumsq + DFEAT);             // N+1
    int*  bsum       = row_start + n_nodes + 1;           // NB (<=64)

    size_t zero_bytes = (3 * (size_t)n_nodes + 2 * DFEAT) * sizeof(int);
    hipMemsetAsync(deg_out_i, 0, zero_bytes, stream);

    hist_kernel<<<(E + 255) / 256, 256, 0, stream>>>(src, dst, deg_out_i, deg_in_i, E);

    scan1_kernel<<<NB, 256, 0, stream>>>(deg_in_i, bsum, n_nodes);
    scan2_kernel<<<1, 64, 0, stream>>>(bsum, row_start, NB, n_nodes);
    scan3_kernel<<<NB, 256, 0, stream>>>(deg_in_i, bsum, row_start, n_nodes);

    fill_kernel<<<(E + 255) / 256, 256, 0, stream>>>(src, dst, deg_out_i, row_start,
                                                     cursor, epack, E);

    int ntiles = (n_nodes + 63) / 64;
    gather_gemm_kernel<<<ntiles, 512, 0, stream>>>(x, row_start, epack, W, bvec,
                                                   out, sums, sumsq, n_nodes);

    int total = n_nodes * DFEAT;
    bn_relu_res_kernel<<<(total + 255) / 256, 256, 0, stream>>>(
        x, sums, sumsq, gamma, beta, out, total, 1.0f / (float)n_nodes);
}